// Round 7
// baseline (1058.685 us; speedup 1.0000x reference)
//
#include <hip/hip_runtime.h>
#include <hip/hip_bf16.h>

#define B_MESH 256
#define VPM    5850
#define NV     (B_MESH * VPM)   // 1497600
#define NE     (3 * NV)         // 4492800
#define KDIM   (VPM * 10)       // 58500
#define KP     58528            // KDIM padded to multiple of 32
#define KSPLIT 64
#define SLOPE  0.01f

// P3 packing (verts, 3ch): 3 x 19-bit biased limbs + 7-bit count.
#define LBIAS 4096
#define LMASK 0x7FFFFull
// x5 packing (5ch in one u64): 13/13/13/13/12 bits at shifts 0/13/26/39/52.
// limb = round(x*S)+bias, S=32 bias=125 (ch0-3), S=16 bias=63 (ch4). Safe deg<=32.
#define S5A   32.f
#define B5A   125
#define S5B   16.f
#define B5B   63
#define CLAMP5 3.9f

typedef short s8v  __attribute__((ext_vector_type(8)));
typedef float f4v  __attribute__((ext_vector_type(4)));

static __device__ __forceinline__ float b2f(__hip_bfloat16 h) { return __bfloat162float(h); }
static __device__ __forceinline__ __hip_bfloat16 f2b(float f) { return __float2bfloat16(f); }
static __device__ __forceinline__ float leaky(float x) { return x >= 0.f ? x : SLOPE * x; }

static __device__ __forceinline__ unsigned long long pack3(float a, float b, float c,
                                                           float S, float clampv)
{
    int ia = __float2int_rn(fminf(fmaxf(a, -clampv), clampv) * S) + LBIAS;
    int ib = __float2int_rn(fminf(fmaxf(b, -clampv), clampv) * S) + LBIAS;
    int ic = __float2int_rn(fminf(fmaxf(c, -clampv), clampv) * S) + LBIAS;
    return (unsigned long long)(unsigned)ia
         | ((unsigned long long)(unsigned)ib << 19)
         | ((unsigned long long)(unsigned)ic << 38)
         | (1ull << 57);
}

static __device__ __forceinline__ void unpack3(unsigned long long p, float invS,
                                               float* o0, float* o1, float* o2, int* cnt)
{
    int c  = (int)(p >> 57);
    int l0 = (int)(p & LMASK);
    int l1 = (int)((p >> 19) & LMASK);
    int l2 = (int)((p >> 38) & LMASK);
    *o0 = (float)(l0 - c * LBIAS) * invS;
    *o1 = (float)(l1 - c * LBIAS) * invS;
    *o2 = (float)(l2 - c * LBIAS) * invS;
    *cnt = c;
}

static __device__ __forceinline__ unsigned long long pack5(const float* x)
{
    unsigned long long p = 0;
#pragma unroll
    for (int c = 0; c < 4; c++) {
        int l = __float2int_rn(fminf(fmaxf(x[c], -CLAMP5), CLAMP5) * S5A) + B5A;
        p |= (unsigned long long)(unsigned)l << (13 * c);
    }
    int l4 = __float2int_rn(fminf(fmaxf(x[4], -CLAMP5), CLAMP5) * S5B) + B5B;
    p |= (unsigned long long)(unsigned)l4 << 52;
    return p;
}

static __device__ __forceinline__ void unpack5(unsigned long long p, int deg, float* o)
{
    const float invA = 1.f / S5A, invB = 1.f / S5B;
#pragma unroll
    for (int c = 0; c < 4; c++) {
        int l = (int)((p >> (13 * c)) & 0x1FFF);
        o[c] = (float)(l - deg * B5A) * invA;
    }
    int l4 = (int)(p >> 52);
    o[4] = (float)(l4 - deg * B5B) * invB;
}

// ---------------- fused init: zero P3/P5/done + pack vq + W2->bf16(pad) + X10 pad zero ----------------
#define INIT_N1 NV                              // phase 1: per-vertex
#define INIT_N2 (64 * KP)                       // phase 2: w2 convert
#define INIT_N3 (B_MESH * (KP - KDIM))          // phase 3: X10 pad
__global__ void initK(const float* __restrict__ verts,
                      unsigned long long* __restrict__ P3,
                      unsigned long long* __restrict__ P5,
                      unsigned long long* __restrict__ vq,
                      const float* __restrict__ W2,
                      __hip_bfloat16* __restrict__ W2b,
                      __hip_bfloat16* __restrict__ X10,
                      int* __restrict__ done)
{
    int t = blockIdx.x * 256 + threadIdx.x;
    if (t < 8) done[t] = 0;
    if (t < INIT_N1) {
        P3[t] = 0ull;
        P5[t] = 0ull;
        float x0 = verts[3 * t + 0], x1 = verts[3 * t + 1], x2 = verts[3 * t + 2];
        vq[t] = pack3(x0, x1, x2, 512.f, 7.9f);
    } else if (t < INIT_N1 + INIT_N2) {
        int idx = t - INIT_N1;
        int n = idx / KP;
        int k = idx - n * KP;
        W2b[idx] = f2b(k < KDIM ? W2[(size_t)n * KDIM + k] : 0.f);
    } else if (t < INIT_N1 + INIT_N2 + INIT_N3) {
        int idx = t - INIT_N1 - INIT_N2;
        int row = idx / (KP - KDIM);
        int c   = idx - row * (KP - KDIM);
        X10[(size_t)row * KP + KDIM + c] = f2b(0.f);
    }
}

// ---------------- scatter 1: one u64 atomic per endpoint ----------------
__global__ void scat1(const int2* __restrict__ edges,
                      const unsigned long long* __restrict__ vq,
                      unsigned long long* __restrict__ P3)
{
    int e = blockIdx.x * 256 + threadIdx.x;
    if (e >= NE) return;
    int2 ij = edges[e];
    unsigned long long qi = vq[ij.x];
    unsigned long long qj = vq[ij.y];
    atomicAdd(&P3[ij.x], qj);
    atomicAdd(&P3[ij.y], qi);
}

// ---------------- conv A (folded); also emit deg8 ----------------
__global__ void convAK(const float* __restrict__ verts,
                       const unsigned long long* __restrict__ P3,
                       const float* __restrict__ w0, const float* __restrict__ b0,
                       const float* __restrict__ w1, const float* __restrict__ b1,
                       unsigned long long* __restrict__ x5q,
                       unsigned char* __restrict__ deg8)
{
    int v = blockIdx.x * 256 + threadIdx.x;
    if (v >= NV) return;
    float x0 = verts[3 * v + 0], x1 = verts[3 * v + 1], x2 = verts[3 * v + 2];
    float s0, s1, s2; int deg;
    unpack3(P3[v], 1.f / 512.f, &s0, &s1, &s2, &deg);
    deg8[v] = (unsigned char)deg;
    float dg = (float)deg;
    float x5[5];
#pragma unroll
    for (int o = 0; o < 5; o++) {
        float a = b0[o] + dg * b1[o]
                + x0 * w0[o * 3 + 0] + x1 * w0[o * 3 + 1] + x2 * w0[o * 3 + 2]
                + s0 * w1[o * 3 + 0] + s1 * w1[o * 3 + 1] + s2 * w1[o * 3 + 2];
        x5[o] = leaky(a);
    }
    x5q[v] = pack5(x5);
}

// ---------------- scatter 5: one u64 atomic per endpoint ----------------
__global__ void scat5(const int2* __restrict__ edges,
                      const unsigned long long* __restrict__ x5q,
                      unsigned long long* __restrict__ P5)
{
    int e = blockIdx.x * 256 + threadIdx.x;
    if (e >= NE) return;
    int2 ij = edges[e];
    unsigned long long qi = x5q[ij.x];
    unsigned long long qj = x5q[ij.y];
    atomicAdd(&P5[ij.x], qj);
    atomicAdd(&P5[ij.y], qi);
}

// ---------------- conv B (folded) + fc1 fused -> X10 bf16 (pitch KP) ----------------
__global__ void convBfc1(const unsigned long long* __restrict__ x5q,
                         const unsigned long long* __restrict__ P5,
                         const unsigned char* __restrict__ deg8,
                         const float* __restrict__ w0, const float* __restrict__ b0,
                         const float* __restrict__ w1, const float* __restrict__ b1,
                         const float* __restrict__ fw, const float* __restrict__ fb,
                         __hip_bfloat16* __restrict__ X10)
{
    int v = blockIdx.x * 256 + threadIdx.x;
    if (v >= NV) return;
    int deg = (int)deg8[v];
    float xc[5], sc[5];
    unpack5(x5q[v], 1, xc);
    unpack5(P5[v], deg, sc);
    float dg = (float)deg;
    float x20[20];
#pragma unroll
    for (int o = 0; o < 20; o++) {
        float a = b0[o] + dg * b1[o];
#pragma unroll
        for (int c = 0; c < 5; c++) a += xc[c] * w0[o * 5 + c] + sc[c] * w1[o * 5 + c];
        x20[o] = leaky(a);
    }
    int row = v / VPM;
    int vi  = v - row * VPM;
    __hip_bfloat16* dst = X10 + (size_t)row * KP + vi * 10;
#pragma unroll
    for (int o2 = 0; o2 < 10; o2++) {
        float a = fb[o2];
#pragma unroll
        for (int o = 0; o < 20; o++) a += x20[o] * fw[o2 * 20 + o];
        dst[o2] = f2b(leaky(a));
    }
}

// ---------------- fused MFMA GEMM + last-block reduce/softmax ----------------
// part[kc][256][64]; grid (8 row-strips of 32, KSPLIT k-chunks), 256 thr = 4 waves.
// Last finishing block per rt reduces its 64 partials + bias and softmaxes 32 rows.
__global__ void gemmSM(const __hip_bfloat16* __restrict__ X10,
                       const __hip_bfloat16* __restrict__ W2b,
                       float* __restrict__ part,
                       int* __restrict__ done,
                       const float* __restrict__ fb2,
                       float* __restrict__ out)
{
    __shared__ int lastFlag;
    int rt = blockIdx.x;               // 0..7
    int kc = blockIdx.y;               // 0..63
    int w    = threadIdx.x >> 6;
    int lane = threadIdx.x & 63;
    int quad = lane >> 4;
    int ml   = lane & 15;
    // 1829 K-steps of 32: 37 chunks of 29 + 27 chunks of 28
    int s0  = kc * 28 + min(kc, 37);
    int len = 28 + (kc < 37 ? 1 : 0);

    const s8v* a0p = (const s8v*)(X10 + (size_t)(rt * 32 + ml) * KP + s0 * 32 + quad * 8);
    const s8v* a1p = (const s8v*)((const __hip_bfloat16*)a0p + (size_t)16 * KP);
    const s8v* bp  = (const s8v*)(W2b + (size_t)(w * 16 + ml) * KP + s0 * 32 + quad * 8);

    f4v c0 = {0.f, 0.f, 0.f, 0.f};
    f4v c1 = {0.f, 0.f, 0.f, 0.f};
    for (int s = 0; s < len; s++) {
        s8v a0 = a0p[s * 4];           // s8v = 16B, K-step 32 bf16 = 4 vectors
        s8v a1 = a1p[s * 4];
        s8v b  = bp[s * 4];
        c0 = __builtin_amdgcn_mfma_f32_16x16x32_bf16(a0, b, c0, 0, 0, 0);
        c1 = __builtin_amdgcn_mfma_f32_16x16x32_bf16(a1, b, c1, 0, 0, 0);
    }
    // C/D: col n = ml, row m = quad*4 + reg
    float* pbase = part + ((size_t)kc * B_MESH + rt * 32) * 64;
#pragma unroll
    for (int r = 0; r < 4; r++) {
        pbase[(quad * 4 + r) * 64 + w * 16 + ml]        = c0[r];
        pbase[(16 + quad * 4 + r) * 64 + w * 16 + ml]   = c1[r];
    }
    // publish, then count completions for this rt
    __threadfence();
    if (threadIdx.x == 0) {
        int prev = atomicAdd(&done[rt], 1);
        lastFlag = (prev == KSPLIT - 1);
    }
    __syncthreads();
    if (!lastFlag) return;

    // last block for this rt: reduce 64 partials for rows [rt*32, rt*32+32) + softmax.
    // wave w handles rows rt*32 + w*8 .. +8; lane = class column.
#pragma unroll
    for (int rr = 0; rr < 8; rr++) {
        int row = rt * 32 + w * 8 + rr;
        float acc = fb2[lane];
        const float* src = part + (size_t)row * 64 + lane;
#pragma unroll 8
        for (int p = 0; p < KSPLIT; p++) acc += src[(size_t)p * B_MESH * 64];
        float m = acc;
#pragma unroll
        for (int off = 32; off; off >>= 1) m = fmaxf(m, __shfl_xor(m, off, 64));
        float e = __expf(acc - m);
        float ssum = e;
#pragma unroll
        for (int off = 32; off; off >>= 1) ssum += __shfl_xor(ssum, off, 64);
        out[row * 64 + lane] = e / ssum;
    }
}

extern "C" void kernel_launch(void* const* d_in, const int* in_sizes, int n_in,
                              void* d_out, int out_size, void* d_ws, size_t ws_size,
                              hipStream_t stream)
{
    const float* verts = (const float*)d_in[0];
    const int*   edges = (const int*)d_in[1];
    const float* w0a   = (const float*)d_in[2];
    const float* b0a   = (const float*)d_in[3];
    const float* w1a   = (const float*)d_in[4];
    const float* b1a   = (const float*)d_in[5];
    const float* w0b   = (const float*)d_in[6];
    const float* b0b   = (const float*)d_in[7];
    const float* w1b   = (const float*)d_in[8];
    const float* b1b   = (const float*)d_in[9];
    const float* fc1w  = (const float*)d_in[10];
    const float* fc1b  = (const float*)d_in[11];
    const float* fc2w  = (const float*)d_in[12];
    const float* fc2b  = (const float*)d_in[13];

    char* ws = (char*)d_ws;
    size_t offP3  = 0;                                     // u64 NV   = 12 MB
    size_t offP5  = offP3  + (size_t)NV * 8;               // u64 NV   = 12 MB
    size_t offVq  = offP5  + (size_t)NV * 8;               // u64 NV   = 12 MB
    size_t offX5q = offVq  + (size_t)NV * 8;               // u64 NV   = 12 MB
    size_t offX10 = offX5q + (size_t)NV * 8;               // bf16 256*KP = 30 MB
    size_t offW2b = offX10 + (size_t)B_MESH * KP * 2;      // bf16 64*KP  = 7.5 MB
    size_t offPt  = offW2b + (size_t)64 * KP * 2;          // f32 64*256*64 = 4 MB
    size_t offDg  = offPt  + (size_t)KSPLIT * B_MESH * 64 * 4; // u8 NV = 1.5 MB
    size_t offDn  = offDg  + (size_t)NV;                   // int[8]
    unsigned long long* P3   = (unsigned long long*)(ws + offP3);
    unsigned long long* P5   = (unsigned long long*)(ws + offP5);
    unsigned long long* vq   = (unsigned long long*)(ws + offVq);
    unsigned long long* x5q  = (unsigned long long*)(ws + offX5q);
    __hip_bfloat16*     X10  = (__hip_bfloat16*)(ws + offX10);
    __hip_bfloat16*     W2b  = (__hip_bfloat16*)(ws + offW2b);
    float*              part = (float*)(ws + offPt);
    unsigned char*      deg8 = (unsigned char*)(ws + offDg);
    int*                done = (int*)(ws + offDn);

    int nvb  = (NV + 255) / 256;                                   // 5850
    int neb  = (NE + 255) / 256;                                   // 17550
    int nib  = (INIT_N1 + INIT_N2 + INIT_N3 + 255) / 256;          // ~20510

    initK<<<nib, 256, 0, stream>>>(verts, P3, P5, vq, fc2w, W2b, X10, done);
    scat1<<<neb, 256, 0, stream>>>((const int2*)edges, vq, P3);
    convAK<<<nvb, 256, 0, stream>>>(verts, P3, w0a, b0a, w1a, b1a, x5q, deg8);
    scat5<<<neb, 256, 0, stream>>>((const int2*)edges, x5q, P5);
    convBfc1<<<nvb, 256, 0, stream>>>(x5q, P5, deg8, w0b, b0b, w1b, b1b, fc1w, fc1b, X10);
    gemmSM<<<dim3(8, KSPLIT), 256, 0, stream>>>(X10, W2b, part, done, fc2b, (float*)d_out);
}

// Round 8
// 976.703 us; speedup vs baseline: 1.0839x; 1.0839x over previous
//
#include <hip/hip_runtime.h>
#include <hip/hip_bf16.h>

#define B_MESH 256
#define VPM    5850
#define NV     (B_MESH * VPM)   // 1497600
#define NE     (3 * NV)         // 4492800
#define NEB    ((NE + 255) / 256)   // 17550 edge blocks
#define KDIM   (VPM * 10)       // 58500
#define KP     58528            // KDIM padded to multiple of 32
#define KSPLIT 64
#define SLOPE  0.01f

// P3 packing (verts, 3ch): 3 x 19-bit biased limbs + 7-bit count.
#define LBIAS 4096
#define LMASK 0x7FFFFull
// x5 packing (5ch in one u64): 13/13/13/13/12 bits at shifts 0/13/26/39/52.
// limb = round(x*S)+bias, S=32 bias=125 (ch0-3), S=16 bias=63 (ch4). Safe deg<=32.
#define S5A   32.f
#define B5A   125
#define S5B   16.f
#define B5B   63
#define CLAMP5 3.9f

// init work carried in scat1's tail blocks
#define W2N    (64 * KP)                 // W2 -> bf16 elements
#define PADN   (B_MESH * (KP - KDIM))    // X10 pad elements

typedef short s8v  __attribute__((ext_vector_type(8)));
typedef float f4v  __attribute__((ext_vector_type(4)));

static __device__ __forceinline__ float b2f(__hip_bfloat16 h) { return __bfloat162float(h); }
static __device__ __forceinline__ __hip_bfloat16 f2b(float f) { return __float2bfloat16(f); }
static __device__ __forceinline__ float leaky(float x) { return x >= 0.f ? x : SLOPE * x; }

static __device__ __forceinline__ unsigned long long pack3(float a, float b, float c,
                                                           float S, float clampv)
{
    int ia = __float2int_rn(fminf(fmaxf(a, -clampv), clampv) * S) + LBIAS;
    int ib = __float2int_rn(fminf(fmaxf(b, -clampv), clampv) * S) + LBIAS;
    int ic = __float2int_rn(fminf(fmaxf(c, -clampv), clampv) * S) + LBIAS;
    return (unsigned long long)(unsigned)ia
         | ((unsigned long long)(unsigned)ib << 19)
         | ((unsigned long long)(unsigned)ic << 38)
         | (1ull << 57);
}

static __device__ __forceinline__ void unpack3(unsigned long long p, float invS,
                                               float* o0, float* o1, float* o2, int* cnt)
{
    int c  = (int)(p >> 57);
    int l0 = (int)(p & LMASK);
    int l1 = (int)((p >> 19) & LMASK);
    int l2 = (int)((p >> 38) & LMASK);
    *o0 = (float)(l0 - c * LBIAS) * invS;
    *o1 = (float)(l1 - c * LBIAS) * invS;
    *o2 = (float)(l2 - c * LBIAS) * invS;
    *cnt = c;
}

static __device__ __forceinline__ unsigned long long pack5(const float* x)
{
    unsigned long long p = 0;
#pragma unroll
    for (int c = 0; c < 4; c++) {
        int l = __float2int_rn(fminf(fmaxf(x[c], -CLAMP5), CLAMP5) * S5A) + B5A;
        p |= (unsigned long long)(unsigned)l << (13 * c);
    }
    int l4 = __float2int_rn(fminf(fmaxf(x[4], -CLAMP5), CLAMP5) * S5B) + B5B;
    p |= (unsigned long long)(unsigned)l4 << 52;
    return p;
}

static __device__ __forceinline__ void unpack5(unsigned long long p, int deg, float* o)
{
    const float invA = 1.f / S5A, invB = 1.f / S5B;
#pragma unroll
    for (int c = 0; c < 4; c++) {
        int l = (int)((p >> (13 * c)) & 0x1FFF);
        o[c] = (float)(l - deg * B5A) * invA;
    }
    int l4 = (int)(p >> 52);
    o[4] = (float)(l4 - deg * B5B) * invB;
}

// ---------------- init (per-vertex only): zero P3/P5 + pack vq ----------------
__global__ void initK(const float* __restrict__ verts,
                      unsigned long long* __restrict__ P3,
                      unsigned long long* __restrict__ P5,
                      unsigned long long* __restrict__ vq)
{
    int t = blockIdx.x * 256 + threadIdx.x;
    if (t >= NV) return;
    P3[t] = 0ull;
    P5[t] = 0ull;
    float x0 = verts[3 * t + 0], x1 = verts[3 * t + 1], x2 = verts[3 * t + 2];
    vq[t] = pack3(x0, x1, x2, 512.f, 7.9f);
}

// ---------------- scatter 1 + free-rider init work in tail blocks ----------------
// Blocks [0,NEB): edge atomics (atomic-op-bound, VALU/BW idle).
// Blocks [NEB,...): W2 fp32->bf16 (K-padded) and X10 pad-zero — independent work
// absorbed by scat1's idle bandwidth.
__global__ void scat1(const int2* __restrict__ edges,
                      const unsigned long long* __restrict__ vq,
                      unsigned long long* __restrict__ P3,
                      const float* __restrict__ W2,
                      __hip_bfloat16* __restrict__ W2b,
                      __hip_bfloat16* __restrict__ X10)
{
    int b = blockIdx.x;
    if (b < NEB) {
        int e = b * 256 + threadIdx.x;
        if (e >= NE) return;
        int2 ij = edges[e];
        unsigned long long qi = vq[ij.x];
        unsigned long long qj = vq[ij.y];
        atomicAdd(&P3[ij.x], qj);
        atomicAdd(&P3[ij.y], qi);
    } else {
        int idx = (b - NEB) * 256 + threadIdx.x;
        if (idx < W2N) {
            int n = idx / KP;
            int k = idx - n * KP;
            W2b[idx] = f2b(k < KDIM ? W2[(size_t)n * KDIM + k] : 0.f);
        } else if (idx < W2N + PADN) {
            int j = idx - W2N;
            int row = j / (KP - KDIM);
            int c   = j - row * (KP - KDIM);
            X10[(size_t)row * KP + KDIM + c] = f2b(0.f);
        }
    }
}

// ---------------- conv A (folded); also emit deg8 ----------------
__global__ void convAK(const float* __restrict__ verts,
                       const unsigned long long* __restrict__ P3,
                       const float* __restrict__ w0, const float* __restrict__ b0,
                       const float* __restrict__ w1, const float* __restrict__ b1,
                       unsigned long long* __restrict__ x5q,
                       unsigned char* __restrict__ deg8)
{
    int v = blockIdx.x * 256 + threadIdx.x;
    if (v >= NV) return;
    float x0 = verts[3 * v + 0], x1 = verts[3 * v + 1], x2 = verts[3 * v + 2];
    float s0, s1, s2; int deg;
    unpack3(P3[v], 1.f / 512.f, &s0, &s1, &s2, &deg);
    deg8[v] = (unsigned char)deg;
    float dg = (float)deg;
    float x5[5];
#pragma unroll
    for (int o = 0; o < 5; o++) {
        float a = b0[o] + dg * b1[o]
                + x0 * w0[o * 3 + 0] + x1 * w0[o * 3 + 1] + x2 * w0[o * 3 + 2]
                + s0 * w1[o * 3 + 0] + s1 * w1[o * 3 + 1] + s2 * w1[o * 3 + 2];
        x5[o] = leaky(a);
    }
    x5q[v] = pack5(x5);
}

// ---------------- scatter 5: one u64 atomic per endpoint ----------------
__global__ void scat5(const int2* __restrict__ edges,
                      const unsigned long long* __restrict__ x5q,
                      unsigned long long* __restrict__ P5)
{
    int e = blockIdx.x * 256 + threadIdx.x;
    if (e >= NE) return;
    int2 ij = edges[e];
    unsigned long long qi = x5q[ij.x];
    unsigned long long qj = x5q[ij.y];
    atomicAdd(&P5[ij.x], qj);
    atomicAdd(&P5[ij.y], qi);
}

// ---------------- conv B (folded) + fc1 fused -> X10 bf16 (pitch KP) ----------------
__global__ void convBfc1(const unsigned long long* __restrict__ x5q,
                         const unsigned long long* __restrict__ P5,
                         const unsigned char* __restrict__ deg8,
                         const float* __restrict__ w0, const float* __restrict__ b0,
                         const float* __restrict__ w1, const float* __restrict__ b1,
                         const float* __restrict__ fw, const float* __restrict__ fb,
                         __hip_bfloat16* __restrict__ X10)
{
    int v = blockIdx.x * 256 + threadIdx.x;
    if (v >= NV) return;
    int deg = (int)deg8[v];
    float xc[5], sc[5];
    unpack5(x5q[v], 1, xc);
    unpack5(P5[v], deg, sc);
    float dg = (float)deg;
    float x20[20];
#pragma unroll
    for (int o = 0; o < 20; o++) {
        float a = b0[o] + dg * b1[o];
#pragma unroll
        for (int c = 0; c < 5; c++) a += xc[c] * w0[o * 5 + c] + sc[c] * w1[o * 5 + c];
        x20[o] = leaky(a);
    }
    int row = v / VPM;
    int vi  = v - row * VPM;
    __hip_bfloat16* dst = X10 + (size_t)row * KP + vi * 10;
#pragma unroll
    for (int o2 = 0; o2 < 10; o2++) {
        float a = fb[o2];
#pragma unroll
        for (int o = 0; o < 20; o++) a += x20[o] * fw[o2 * 20 + o];
        dst[o2] = f2b(leaky(a));
    }
}

// ---------------- MFMA GEMM: part[kc][256][64] = X10[256][KP](bf16) @ W2b[64][KP]^T ----------------
// grid (8 row-strips of 32, KSPLIT k-chunks) = 512 blocks (2/CU), 256 thr = 4 waves
__global__ void gemmMFMA(const __hip_bfloat16* __restrict__ X10,
                         const __hip_bfloat16* __restrict__ W2b,
                         float* __restrict__ part)
{
    int rt = blockIdx.x;               // 0..7
    int kc = blockIdx.y;               // 0..63
    int w    = threadIdx.x >> 6;
    int lane = threadIdx.x & 63;
    int quad = lane >> 4;
    int ml   = lane & 15;
    // 1829 K-steps of 32: 37 chunks of 29 + 27 chunks of 28
    int s0  = kc * 28 + min(kc, 37);
    int len = 28 + (kc < 37 ? 1 : 0);

    const s8v* a0p = (const s8v*)(X10 + (size_t)(rt * 32 + ml) * KP + s0 * 32 + quad * 8);
    const s8v* a1p = (const s8v*)((const __hip_bfloat16*)a0p + (size_t)16 * KP);
    const s8v* bp  = (const s8v*)(W2b + (size_t)(w * 16 + ml) * KP + s0 * 32 + quad * 8);

    f4v c0 = {0.f, 0.f, 0.f, 0.f};
    f4v c1 = {0.f, 0.f, 0.f, 0.f};
    for (int s = 0; s < len; s++) {
        s8v a0 = a0p[s * 4];           // s8v = 16B, K-step 32 bf16 = 4 vectors
        s8v a1 = a1p[s * 4];
        s8v b  = bp[s * 4];
        c0 = __builtin_amdgcn_mfma_f32_16x16x32_bf16(a0, b, c0, 0, 0, 0);
        c1 = __builtin_amdgcn_mfma_f32_16x16x32_bf16(a1, b, c1, 0, 0, 0);
    }
    // C/D: col n = ml, row m = quad*4 + reg
    float* pbase = part + ((size_t)kc * B_MESH + rt * 32) * 64;
#pragma unroll
    for (int r = 0; r < 4; r++) {
        pbase[(quad * 4 + r) * 64 + w * 16 + ml]        = c0[r];
        pbase[(16 + quad * 4 + r) * 64 + w * 16 + ml]   = c1[r];
    }
}

// ---------------- reduce partials + bias + softmax ----------------
__global__ void reduceSoftmax(const float* __restrict__ part,
                              const float* __restrict__ fb2,
                              float* __restrict__ out)
{
    int b = blockIdx.x;
    int n = threadIdx.x;   // 64
    float acc = fb2[n];
#pragma unroll 8
    for (int p = 0; p < KSPLIT; p++) acc += part[((size_t)p * B_MESH + b) * 64 + n];
    float m = acc;
#pragma unroll
    for (int off = 32; off; off >>= 1) m = fmaxf(m, __shfl_xor(m, off, 64));
    float e = __expf(acc - m);
    float s = e;
#pragma unroll
    for (int off = 32; off; off >>= 1) s += __shfl_xor(s, off, 64);
    out[b * 64 + n] = e / s;
}

extern "C" void kernel_launch(void* const* d_in, const int* in_sizes, int n_in,
                              void* d_out, int out_size, void* d_ws, size_t ws_size,
                              hipStream_t stream)
{
    const float* verts = (const float*)d_in[0];
    const int*   edges = (const int*)d_in[1];
    const float* w0a   = (const float*)d_in[2];
    const float* b0a   = (const float*)d_in[3];
    const float* w1a   = (const float*)d_in[4];
    const float* b1a   = (const float*)d_in[5];
    const float* w0b   = (const float*)d_in[6];
    const float* b0b   = (const float*)d_in[7];
    const float* w1b   = (const float*)d_in[8];
    const float* b1b   = (const float*)d_in[9];
    const float* fc1w  = (const float*)d_in[10];
    const float* fc1b  = (const float*)d_in[11];
    const float* fc2w  = (const float*)d_in[12];
    const float* fc2b  = (const float*)d_in[13];

    char* ws = (char*)d_ws;
    size_t offP3  = 0;                                     // u64 NV   = 12 MB
    size_t offP5  = offP3  + (size_t)NV * 8;               // u64 NV   = 12 MB
    size_t offVq  = offP5  + (size_t)NV * 8;               // u64 NV   = 12 MB
    size_t offX5q = offVq  + (size_t)NV * 8;               // u64 NV   = 12 MB
    size_t offX10 = offX5q + (size_t)NV * 8;               // bf16 256*KP = 30 MB
    size_t offW2b = offX10 + (size_t)B_MESH * KP * 2;      // bf16 64*KP  = 7.5 MB
    size_t offPt  = offW2b + (size_t)64 * KP * 2;          // f32 64*256*64 = 4 MB
    size_t offDg  = offPt  + (size_t)KSPLIT * B_MESH * 64 * 4; // u8 NV = 1.5 MB
    unsigned long long* P3   = (unsigned long long*)(ws + offP3);
    unsigned long long* P5   = (unsigned long long*)(ws + offP5);
    unsigned long long* vq   = (unsigned long long*)(ws + offVq);
    unsigned long long* x5q  = (unsigned long long*)(ws + offX5q);
    __hip_bfloat16*     X10  = (__hip_bfloat16*)(ws + offX10);
    __hip_bfloat16*     W2b  = (__hip_bfloat16*)(ws + offW2b);
    float*              part = (float*)(ws + offPt);
    unsigned char*      deg8 = (unsigned char*)(ws + offDg);

    int nvb   = (NV + 255) / 256;                      // 5850
    int ntail = (W2N + PADN + 255) / 256;              // ~14661
    int ns1   = NEB + ntail;                           // scat1 grid incl. free-riders

    initK<<<nvb, 256, 0, stream>>>(verts, P3, P5, vq);
    scat1<<<ns1, 256, 0, stream>>>((const int2*)edges, vq, P3, fc2w, W2b, X10);
    convAK<<<nvb, 256, 0, stream>>>(verts, P3, w0a, b0a, w1a, b1a, x5q, deg8);
    scat5<<<NEB, 256, 0, stream>>>((const int2*)edges, x5q, P5);
    convBfc1<<<nvb, 256, 0, stream>>>(x5q, P5, deg8, w0b, b0b, w1b, b1b, fc1w, fc1b, X10);
    gemmMFMA<<<dim3(8, KSPLIT), 256, 0, stream>>>(X10, W2b, part);
    reduceSoftmax<<<B_MESH, 64, 0, stream>>>(part, fc2b, (float*)d_out);
}